// Round 9
// baseline (33.116 us; speedup 1.0000x reference)
//
#include <hip/hip_runtime.h>

#define IN_SIZE 11
#define HID 16
#define FEAT 18
#define TSTEPS 18

__device__ __forceinline__ float fast_rcp(float v) { return __builtin_amdgcn_rcpf(v); }

// broadcast a float from a fixed lane via v_readlane (SGPR path, no DS)
__device__ __forceinline__ float rl(float v, int lane) {
    return __int_as_float(__builtin_amdgcn_readlane(__float_as_int(v), lane));
}

// One WAVE per graph. Lane wl owns gate row wl (r=wl>>4, u=wl&15).
// Search: dual lower_bound in 32-lane halves (lanes 0-31 -> g, 32-63 -> g+1),
// 256-ary rounds (8 independent probes/lane, ballot-counted):
//   8M -> 31250 -> 122 (2 rounds; round 1 addresses are grid-constant =
//   L2-shared, round 2 windows shared by ~32 waves) + one fat contiguous
//   final round (8 probes/lane covering the <=256 window exactly).
// 3 dependent memory rounds total (r6 had 5). Gather + LSTM from r6.
extern "C" __global__ __launch_bounds__(256, 4)
void tgnn_lstm_fused(const float* __restrict__ x,
                     const float* __restrict__ W_ih,
                     const float* __restrict__ W_hh,
                     const float* __restrict__ b_ih,
                     const float* __restrict__ b_hh,
                     const float* __restrict__ W_fc,
                     const float* __restrict__ b_fc,
                     const int* __restrict__ edge_index,
                     const int* __restrict__ edge_attr,
                     const int* __restrict__ batch,
                     float* __restrict__ out,
                     int E, int B)
{
    const int wl  = threadIdx.x & 63;
    const int g   = (blockIdx.x * blockDim.x + threadIdx.x) >> 6;  // wave = graph
    const int u   = wl & 15;
    const int r   = wl >> 4;
    const int row = wl;

    // ---- dual lower_bound, 256-ary (8 probes/lane), halves: g and g+1 ----
    const int vt  = g + (wl >> 5);
    const int l32 = wl & 31;
    int lo = 0, hi = E;
    int n = hi - lo;
    while (n > 256) {
        unsigned c = 0;
#pragma unroll
        for (int e = 0; e < 8; ++e) {
            const unsigned i8 = (unsigned)(l32 * 8 + e);            // probe 0..255
            const int p = lo + (int)(((unsigned)n * i8) >> 8);      // < hi <= E
            const bool lt = batch[p] < vt;
            const unsigned long long bal = __ballot(lt);
            c += (wl < 32) ? __popc((unsigned)bal)
                           : __popc((unsigned)(bal >> 32));
        }
        const int nlo = c ? (lo + (int)(((unsigned)n * (c - 1)) >> 8) + 1) : lo;
        const int nhi = (c < 256u) ? (lo + (int)(((unsigned)n * c) >> 8)) : hi;
        lo = nlo; hi = nhi; n = hi - lo;
    }
    {   // fat final: 8 contiguous probes/lane cover [lo, lo+256) >= [lo, hi)
        unsigned cf = 0;
#pragma unroll
        for (int e = 0; e < 8; ++e) {
            const int idx = lo + l32 * 8 + e;
            int a2 = idx; if (a2 > E - 1) a2 = E - 1;
            const bool lt = (idx < hi) && (batch[a2] < vt);
            const unsigned long long bal = __ballot(lt);
            cf += (wl < 32) ? __popc((unsigned)bal)
                            : __popc((unsigned)(bal >> 32));
        }
        lo += (int)cf;                   // = lower_bound(batch, vt)
    }
    const int f0 = __builtin_amdgcn_readlane(lo, 0);    // first edge of g
    const int f1 = __builtin_amdgcn_readlane(lo, 32);   // first edge of g+1
    int cnt = f1 - f0;
    cnt = (cnt < 0) ? 0 : ((cnt > TSTEPS) ? TSTEPS : cnt);

    // ---- edge fetch FIRST (oldest in VMEM queue), weights issued behind ----
    int n1 = 0, n2 = 0, ea = 0;
    if (wl < TSTEPS) {
        int j = f0 + wl;
        if (j > E - 1) j = E - 1;
        n1 = edge_index[j];
        n2 = edge_index[E + j];
        ea = edge_attr[j];               // in [0,7) even when clamped
    }

    // ---- per-lane weights: off the critical path (overlap edge/x rounds) ----
    float wih[IN_SIZE], whh[HID];
#pragma unroll
    for (int k = 0; k < IN_SIZE; ++k) wih[k] = W_ih[row * FEAT + k];
#pragma unroll
    for (int v = 0; v < HID; ++v) whh[v] = W_hh[row * HID + v];
    const float bias = b_ih[row] + b_hh[row];
    const float wfc  = W_fc[row];
    const float bfc  = b_fc[r];

    // ---- x gather: lane t holds step t's 11 summed features (one round) ----
    float f[IN_SIZE];
    {
        const float* xa = x + (long)n1 * IN_SIZE;
        const float* xb = x + (long)n2 * IN_SIZE;
#pragma unroll
        for (int k = 0; k < IN_SIZE; ++k) f[k] = xa[k] + xb[k];
    }
    if (wl >= cnt) {                     // invalid steps AND lanes >= 18
#pragma unroll
        for (int k = 0; k < IN_SIZE; ++k) f[k] = 0.0f;
    }

    // ---- prologue: a_in[t] = bias + x_t . wih_row + onehot-weight (per lane) ----
    float ain[TSTEPS];
#pragma unroll
    for (int t = 0; t < TSTEPS; ++t) {
        const int eat = __builtin_amdgcn_readlane(ea, t);   // uniform
        const float w1 = W_ih[row * FEAT + IN_SIZE + eat];  // L1-hot (same lines as wih)
        float a = bias + ((t < cnt) ? w1 : 0.0f);
#pragma unroll
        for (int k = 0; k < IN_SIZE; ++k)
            a = fmaf(rl(f[k], t), wih[k], a);
        ain[t] = a;
    }

    // ---- LSTM: per step 16 readlane + 16 FMA + 1 own-gate act + 3 swizzles ----
    const float sa = (r == 2) ? -2.0f : -1.0f;   // r==2 -> tanh via 2*sig(2a)-1
    const float ma = (r == 2) ?  2.0f :  1.0f;
    const float oa = (r == 2) ? -1.0f :  0.0f;

    float h = 0.0f, c = 0.0f;
#pragma unroll
    for (int t = 0; t < TSTEPS; ++t) {
        float a;
        if (t == 0) {
            a = ain[0];
        } else {
            float A0 = ain[t], A1 = 0.0f, A2 = 0.0f, A3 = 0.0f;
#pragma unroll
            for (int v = 0; v < HID; v += 4) {
                A0 = fmaf(rl(h, v + 0), whh[v + 0], A0);
                A1 = fmaf(rl(h, v + 1), whh[v + 1], A1);
                A2 = fmaf(rl(h, v + 2), whh[v + 2], A2);
                A3 = fmaf(rl(h, v + 3), whh[v + 3], A3);
            }
            a = (A0 + A1) + (A2 + A3);
        }
        const float act = fmaf(ma, fast_rcp(1.0f + __expf(sa * a)), oa);
        const float s1 = __shfl_xor(act, 16, 64);   // sigma(f)
        const float s2 = __shfl_xor(act, 32, 64);   // tanh(g)
        const float s3 = __shfl_xor(s1, 32, 64);    // sigma(o)
        c = fmaf(s1, c, act * s2);                  // lanes 0..15 valid
        const float th = fmaf(2.0f, fast_rcp(1.0f + __expf(-2.0f * c)), -1.0f);
        h = s3 * th;
    }

    // ---- fc epilogue ----
    const float hb = __shfl(h, u, 64);              // lane wl <- h[u] from lane u
    float p = hb * wfc;                             // W_fc[r][u] == W_fc[row]
#pragma unroll
    for (int m = 8; m >= 1; m >>= 1) p += __shfl_xor(p, m, 16);
    if (u == 0 && g < B) out[g * 4 + r] = p + bfc;
}

extern "C" void kernel_launch(void* const* d_in, const int* in_sizes, int n_in,
                              void* d_out, int out_size, void* d_ws, size_t ws_size,
                              hipStream_t stream) {
    const float* x     = (const float*)d_in[0];
    const float* W_ih  = (const float*)d_in[1];
    const float* W_hh  = (const float*)d_in[2];
    const float* b_ih  = (const float*)d_in[3];
    const float* b_hh  = (const float*)d_in[4];
    const float* W_fc  = (const float*)d_in[5];
    const float* b_fc  = (const float*)d_in[6];
    const int* edge_index = (const int*)d_in[7];
    const int* edge_attr  = (const int*)d_in[8];
    const int* batch      = (const int*)d_in[9];

    const int E = in_sizes[8];       // N_EDGES
    const int B = out_size / 4;      // N_GRAPHS

    const int grid = (B + 3) / 4;    // 4 graphs (waves) per 256-thread block
    tgnn_lstm_fused<<<grid, 256, 0, stream>>>(x, W_ih, W_hh, b_ih, b_hh,
                                              W_fc, b_fc,
                                              edge_index, edge_attr, batch,
                                              (float*)d_out, E, B);
}